// Round 6
// baseline (102.449 us; speedup 1.0000x reference)
//
#include <hip/hip_runtime.h>
#include <hip/hip_fp16.h>

typedef __attribute__((ext_vector_type(8))) _Float16 f16x8;
typedef __attribute__((ext_vector_type(4))) _Float16 f16x4;
typedef __attribute__((ext_vector_type(8))) unsigned short u16x8;
typedef __attribute__((ext_vector_type(4))) float f32x4;

constexpr int NT = 256;
constexpr int TILE_SHORTS = 4096;   // 64 rows x 64 fp16 = 8KB tile image

// phys 16B-chunk swizzle: row r, logical chunk c (0..7) -> short offset
__device__ __forceinline__ int swzoff(int row, int c) {
    return row * 64 + ((c ^ (row & 7)) << 3);
}
__device__ __forceinline__ unsigned short f2h_u(float x) {
    return __half_as_ushort(__float2half(x));
}

// ============ pre-pass: f32 -> fp16 swizzled tile images in ws ============
__global__ __launch_bounds__(256, 4) void prepass(
    const float* __restrict__ Kg, const float* __restrict__ Vg,
    unsigned short* __restrict__ Kw, unsigned short* __restrict__ Vw)
{
    __shared__ __align__(16) float Vl[64 * 68];
    const int tile = blockIdx.x;      // 0..31
    const int bh   = blockIdx.y;      // 0..15
    const int b = bh >> 3, h = bh & 7;
    const int tid = threadIdx.x;
    const size_t gbase = (((size_t)b * 2048 + tile * 64) * 8 + h) * 64;

    // stage V tile f32 into LDS (coalesced)
    #pragma unroll
    for (int j = 0; j < 4; ++j) {
        int id = j * 256 + tid, row = id >> 4, c4 = id & 15;
        *(float4*)&Vl[row * 68 + c4 * 4] =
            *(const float4*)&Vg[gbase + (size_t)row * 512 + c4 * 4];
    }

    // K image: row-major fp16, 16B chunks XOR-swizzled
    unsigned short* Ko = Kw + (size_t)(bh * 32 + tile) * TILE_SHORTS;
    #pragma unroll
    for (int j = 0; j < 2; ++j) {
        int id = j * 256 + tid, row = id >> 3, c = id & 7;
        const float* src = &Kg[gbase + (size_t)row * 512 + c * 8];
        float4 x = *(const float4*)src, y = *(const float4*)(src + 4);
        u16x8 o;
        o[0] = f2h_u(x.x); o[1] = f2h_u(x.y); o[2] = f2h_u(x.z); o[3] = f2h_u(x.w);
        o[4] = f2h_u(y.x); o[5] = f2h_u(y.y); o[6] = f2h_u(y.z); o[7] = f2h_u(y.w);
        *(u16x8*)&Ko[swzoff(row, c)] = o;
    }
    __syncthreads();

    // V^T image, k-permuted so one b128 = the 4 B-frags of 16x16x16 PV:
    // store at k' = quad*16 + c*4 + i the element k = c*16 + quad*4 + i
    unsigned short* Vo = Vw + (size_t)(bh * 32 + tile) * TILE_SHORTS;
    #pragma unroll
    for (int j = 0; j < 2; ++j) {
        int id = j * 256 + tid, vrow = id >> 3, g = id & 7;
        u16x8 o;
        #pragma unroll
        for (int jj = 0; jj < 8; ++jj) {
            int kk = ((g & 1) * 2 + (jj >> 2)) * 16 + (g >> 1) * 4 + (jj & 3);
            o[jj] = f2h_u(Vl[kk * 68 + vrow]);
        }
        *(u16x8*)&Vo[swzoff(vrow, g)] = o;
    }
}

// ============ main kernel: no LDS, no barriers, register-prefetched ============
__global__ __launch_bounds__(NT, 2) void attn_pow2_f16(
    const float* __restrict__ Qg,
    const unsigned short* __restrict__ Kw, const unsigned short* __restrict__ Vw,
    float* __restrict__ Og)
{
    const int tid  = threadIdx.x;
    const int lane = tid & 63;
    const int wave = tid >> 6;
    const int a    = lane & 15;
    const int quad = lane >> 4;
    const int m0   = wave * 16;

    // heavy+light pairing swizzle (bijection over 512 blocks)
    int r0 = (int)blockIdx.x;
    int wr = (r0 < 256) ? r0 : (767 - r0);
    const int qt = 31 - (wr >> 4);
    const int bh = wr & 15;
    const int b = bh >> 3, h = bh & 7;
    const int q0 = qt * 64;

    // ---- Q B-frags from global f32: B[n=q=a][k=d=ks*32+quad*8+j] ----
    f16x8 bQ[2];
    {
        const size_t qrowbase = (((size_t)b * 2048 + q0 + m0 + a) * 8 + h) * 64;
        #pragma unroll
        for (int ks = 0; ks < 2; ++ks) {
            const float* src = &Qg[qrowbase + ks * 32 + quad * 8];
            float4 x = *(const float4*)src, y = *(const float4*)(src + 4);
            u16x8 o;
            o[0] = f2h_u(x.x); o[1] = f2h_u(x.y); o[2] = f2h_u(x.z); o[3] = f2h_u(x.w);
            o[4] = f2h_u(y.x); o[5] = f2h_u(y.y); o[6] = f2h_u(y.z); o[7] = f2h_u(y.w);
            bQ[ks] = __builtin_bit_cast(f16x8, o);
        }
    }

    const unsigned short* Ktiles = Kw + (size_t)bh * 32 * TILE_SHORTS;
    const unsigned short* Vtiles = Vw + (size_t)bh * 32 * TILE_SHORTS;

    // per-wave fragment offsets within a tile image (shorts)
    int koff[8], voff[8];
    #pragma unroll
    for (int s = 0; s < 4; ++s) {
        koff[s * 2 + 0] = swzoff(s * 16 + a, quad);          // ks=0
        koff[s * 2 + 1] = swzoff(s * 16 + a, 4 + quad);      // ks=1
        voff[s * 2 + 0] = swzoff(s * 16 + a, quad * 2);
        voff[s * 2 + 1] = swzoff(s * 16 + a, quad * 2 + 1);
    }

    u16x8 c0K[8], c0V[8], c1K[8], c1V[8];
    auto gload = [&](int kt, u16x8 (&rk)[8], u16x8 (&rv)[8]) {
        const unsigned short* kg = Ktiles + (size_t)kt * TILE_SHORTS;
        const unsigned short* vg = Vtiles + (size_t)kt * TILE_SHORTS;
        #pragma unroll
        for (int i = 0; i < 8; ++i) {
            rk[i] = *(const u16x8*)&kg[koff[i]];
            rv[i] = *(const u16x8*)&vg[voff[i]];
        }
    };

    f32x4 oacc[4];
    #pragma unroll
    for (int n = 0; n < 4; ++n) oacc[n] = (f32x4){0.f, 0.f, 0.f, 0.f};
    float den_l = 0.f;

    union U8 { u16x8 u; f16x4 q[2]; f16x8 f; };

    auto compute = [&](const u16x8 (&rk)[8], const u16x8 (&rv)[8], bool diag) {
        // ---- S^T = K·Q^T: C-layout of S^T == A-layout of S ----
        f32x4 sacc[4];
        #pragma unroll
        for (int s = 0; s < 4; ++s) sacc[s] = (f32x4){0.f, 0.f, 0.f, 0.f};
        #pragma unroll
        for (int s = 0; s < 4; ++s) {
            #pragma unroll
            for (int ks = 0; ks < 2; ++ks) {
                U8 ak; ak.u = rk[s * 2 + ks];
                sacc[s] = __builtin_amdgcn_mfma_f32_16x16x32_f16(ak.f, bQ[ks], sacc[s], 0, 0, 0);
            }
        }
        // ---- square, mask (diag), den, convert in-register ----
        f16x4 aS[4];
        #pragma unroll
        for (int s = 0; s < 4; ++s) {
            float p[4];
            #pragma unroll
            for (int r = 0; r < 4; ++r) {
                float d0 = sacc[s][r];
                float v = d0 * d0;
                if (diag && (s * 16 + quad * 4 + r) > (m0 + a)) v = 0.f;
                p[r] = v;
            }
            den_l += (p[0] + p[1]) + (p[2] + p[3]);
            aS[s] = (f16x4){(_Float16)p[0], (_Float16)p[1], (_Float16)p[2], (_Float16)p[3]};
        }
        // ---- PV: O += S·V via 16x16x16; S^T C-regs feed A directly ----
        #pragma unroll
        for (int n = 0; n < 4; ++n) {
            U8 va, vb;
            va.u = rv[n * 2 + 0];
            vb.u = rv[n * 2 + 1];
            oacc[n] = __builtin_amdgcn_mfma_f32_16x16x16f16(aS[0], va.q[0], oacc[n], 0, 0, 0);
            oacc[n] = __builtin_amdgcn_mfma_f32_16x16x16f16(aS[1], va.q[1], oacc[n], 0, 0, 0);
            oacc[n] = __builtin_amdgcn_mfma_f32_16x16x16f16(aS[2], vb.q[0], oacc[n], 0, 0, 0);
            oacc[n] = __builtin_amdgcn_mfma_f32_16x16x16f16(aS[3], vb.q[1], oacc[n], 0, 0, 0);
        }
    };

    // ping-pong over key tiles, prefetch depth 1, no barriers anywhere
    gload(0, c0K, c0V);
    for (int kt = 0; kt <= qt; kt += 2) {
        if (kt + 1 <= qt) gload(kt + 1, c1K, c1V);
        compute(c0K, c0V, kt == qt);
        if (kt + 1 <= qt) {
            if (kt + 2 <= qt) gload(kt + 2, c0K, c0V);
            compute(c1K, c1V, kt + 1 == qt);
        }
    }

    // ---- den: reduce across quads (same q=a), gather per output row ----
    den_l += __shfl_xor(den_l, 16);
    den_l += __shfl_xor(den_l, 32);

    float invz[4];
    #pragma unroll
    for (int r = 0; r < 4; ++r) {
        float dq = __shfl(den_l, quad * 4 + r);   // lane holding a == quad*4+r
        invz[r] = 1.0f / (dq + 1e-5f);
    }

    #pragma unroll
    for (int n = 0; n < 4; ++n) {
        #pragma unroll
        for (int r = 0; r < 4; ++r) {
            int t = q0 + m0 + quad * 4 + r;
            int v = n * 16 + a;
            Og[(((size_t)b * 2048 + t) * 8 + h) * 64 + v] = oacc[n][r] * invz[r];
        }
    }
}

extern "C" void kernel_launch(void* const* d_in, const int* in_sizes, int n_in,
                              void* d_out, int out_size, void* d_ws, size_t ws_size,
                              hipStream_t stream) {
    const float* Q = (const float*)d_in[0];
    const float* K = (const float*)d_in[1];
    const float* V = (const float*)d_in[2];
    float* O = (float*)d_out;
    unsigned short* Kw = (unsigned short*)d_ws;                 // 4 MB
    unsigned short* Vw = Kw + (size_t)16 * 32 * TILE_SHORTS;    // 4 MB

    prepass<<<dim3(32, 16), 256, 0, stream>>>(K, V, Kw, Vw);
    attn_pow2_f16<<<dim3(512), NT, 0, stream>>>(Q, Kw, Vw, O);
}

// Round 7
// 99.729 us; speedup vs baseline: 1.0273x; 1.0273x over previous
//
#include <hip/hip_runtime.h>
#include <hip/hip_fp16.h>

typedef __attribute__((ext_vector_type(8))) _Float16 f16x8;
typedef __attribute__((ext_vector_type(4))) _Float16 f16x4;
typedef __attribute__((ext_vector_type(8))) unsigned short u16x8;
typedef __attribute__((ext_vector_type(4))) float f32x4;

constexpr int NT = 512;
constexpr int TILE_SHORTS = 4096;   // 64 rows x 64 fp16 = 8KB tile image

// phys 16B-chunk swizzle: row r, logical chunk c (0..7) -> short offset
__device__ __forceinline__ int swzoff(int row, int c) {
    return row * 64 + ((c ^ (row & 7)) << 3);
}
__device__ __forceinline__ unsigned short f2h_u(float x) {
    return __half_as_ushort(__float2half(x));
}

// ============ pre-pass: f32 -> fp16 swizzled tile images in ws (R5-verified) ============
__global__ __launch_bounds__(256, 4) void prepass(
    const float* __restrict__ Kg, const float* __restrict__ Vg,
    unsigned short* __restrict__ Kw, unsigned short* __restrict__ Vw)
{
    __shared__ __align__(16) float Vl[64 * 68];
    const int tile = blockIdx.x;      // 0..31
    const int bh   = blockIdx.y;      // 0..15
    const int b = bh >> 3, h = bh & 7;
    const int tid = threadIdx.x;
    const size_t gbase = (((size_t)b * 2048 + tile * 64) * 8 + h) * 64;

    #pragma unroll
    for (int j = 0; j < 4; ++j) {
        int id = j * 256 + tid, row = id >> 4, c4 = id & 15;
        *(float4*)&Vl[row * 68 + c4 * 4] =
            *(const float4*)&Vg[gbase + (size_t)row * 512 + c4 * 4];
    }

    unsigned short* Ko = Kw + (size_t)(bh * 32 + tile) * TILE_SHORTS;
    #pragma unroll
    for (int j = 0; j < 2; ++j) {
        int id = j * 256 + tid, row = id >> 3, c = id & 7;
        const float* src = &Kg[gbase + (size_t)row * 512 + c * 8];
        float4 x = *(const float4*)src, y = *(const float4*)(src + 4);
        u16x8 o;
        o[0] = f2h_u(x.x); o[1] = f2h_u(x.y); o[2] = f2h_u(x.z); o[3] = f2h_u(x.w);
        o[4] = f2h_u(y.x); o[5] = f2h_u(y.y); o[6] = f2h_u(y.z); o[7] = f2h_u(y.w);
        *(u16x8*)&Ko[swzoff(row, c)] = o;
    }
    __syncthreads();

    // V^T image, k-permuted: store at k' = quad*16 + c*4 + i the element
    // k = c*16 + quad*4 + i  (one b128 = the 4 B-frags of 16x16x16 PV)
    unsigned short* Vo = Vw + (size_t)(bh * 32 + tile) * TILE_SHORTS;
    #pragma unroll
    for (int j = 0; j < 2; ++j) {
        int id = j * 256 + tid, vrow = id >> 3, g = id & 7;
        u16x8 o;
        #pragma unroll
        for (int jj = 0; jj < 8; ++jj) {
            int kk = ((g & 1) * 2 + (jj >> 2)) * 16 + (g >> 1) * 4 + (jj & 3);
            o[jj] = f2h_u(Vl[kk * 68 + vrow]);
        }
        *(u16x8*)&Vo[swzoff(vrow, g)] = o;
    }
}

// ============ main kernel: 256 equal-length blocks, 8 waves, 4 key-groups ============
__global__ __launch_bounds__(NT, 2) void attn_pow2_f16(
    const float* __restrict__ Qg,
    const unsigned short* __restrict__ Kw, const unsigned short* __restrict__ Vw,
    float* __restrict__ Og)
{
    __shared__ __align__(16) unsigned short lds[4 * 2 * TILE_SHORTS];  // 64 KiB
    const int tid  = threadIdx.x;
    const int lane = tid & 63;
    const int wave = tid >> 6;      // 0..7
    const int g    = wave >> 1;     // key-group: kt ≡ g (mod 4)
    const int w2   = wave & 1;      // q-half: rows w2*32 .. +31
    const int a    = lane & 15;
    const int quad = lane >> 4;
    const int gt   = tid & 127;     // thread-in-group (2 waves = 128 thr)

    const int r0 = (int)blockIdx.x;         // 256 blocks, ALL length 9
    const int bh = r0 & 15, p = r0 >> 4;    // p = 0..15
    const int b = bh >> 3, h = bh & 7;
    const int TqA = 31 - p, TqB = p;        // sequential q-tile pair
    const int IA = (TqA + 4) >> 2;          // ceil((TqA+1)/4); IA + IB == 9

    const unsigned short* Ktiles = Kw + (size_t)bh * 32 * TILE_SHORTS;
    const unsigned short* Vtiles = Vw + (size_t)bh * 32 * TILE_SHORTS;
    unsigned short* const Kb = lds + g * (2 * TILE_SHORTS);   // per-group stage
    unsigned short* const Vb = Kb + TILE_SHORTS;

    union U8 { u16x8 u; f16x4 q[2]; f16x8 f; };

    // ---- Q B-frags for this wave's 2 q-strips: B[n=q=a][k=ks*32+quad*8+j] ----
    f16x8 bQ[2][2];
    auto loadBQ = [&](int Tq) {
        #pragma unroll
        for (int st = 0; st < 2; ++st) {
            const size_t rowbase =
                (((size_t)b * 2048 + Tq * 64 + w2 * 32 + st * 16 + a) * 8 + h) * 64;
            #pragma unroll
            for (int ks = 0; ks < 2; ++ks) {
                const float* src = &Qg[rowbase + ks * 32 + quad * 8];
                float4 x = *(const float4*)src, y = *(const float4*)(src + 4);
                u16x8 o;
                o[0] = f2h_u(x.x); o[1] = f2h_u(x.y); o[2] = f2h_u(x.z); o[3] = f2h_u(x.w);
                o[4] = f2h_u(y.x); o[5] = f2h_u(y.y); o[6] = f2h_u(y.z); o[7] = f2h_u(y.w);
                bQ[st][ks] = __builtin_bit_cast(f16x8, o);
            }
        }
    };
    loadBQ(TqA);

    // register-staged tile prefetch (byte-copy of pre-swizzled 8KB images)
    u16x8 rK[4], rV[4];
    auto gload = [&](int kt) {
        const u16x8* kg = (const u16x8*)(Ktiles + (size_t)kt * TILE_SHORTS);
        const u16x8* vg = (const u16x8*)(Vtiles + (size_t)kt * TILE_SHORTS);
        #pragma unroll
        for (int j = 0; j < 4; ++j) { rK[j] = kg[j * 128 + gt]; rV[j] = vg[j * 128 + gt]; }
    };
    gload(g);   // kt=g <= TqA (TqA >= 16) always valid in phase A

    f32x4 oacc[2][4];
    #pragma unroll
    for (int st = 0; st < 2; ++st)
        #pragma unroll
        for (int n = 0; n < 4; ++n) oacc[st][n] = (f32x4){0.f, 0.f, 0.f, 0.f};
    float den[2] = {0.f, 0.f};

    for (int it = 0; it < 9; ++it) {
        const bool inB = it >= IA;
        const int  i   = inB ? it - IA : it;
        const int  Tq  = inB ? TqB : TqA;
        const int  kt  = i * 4 + g;
        const bool valid = kt <= Tq;

        if (valid) {   // write staged regs -> group's LDS buffer (contiguous b128)
            u16x8* kd = (u16x8*)Kb; u16x8* vd = (u16x8*)Vb;
            #pragma unroll
            for (int j = 0; j < 4; ++j) { kd[j * 128 + gt] = rK[j]; vd[j * 128 + gt] = rV[j]; }
        }
        __syncthreads();   // stage visible

        {   // prefetch next tile into registers (drains under compute)
            const int itn = it + 1;
            if (itn < 9) {
                const bool inBn = itn >= IA;
                const int  in_  = inBn ? itn - IA : itn;
                const int  ktn  = in_ * 4 + g;
                if (ktn <= (inBn ? TqB : TqA)) gload(ktn);
            }
        }

        if (valid) {
            // ---- S^T = K·Q^T for both q-strips (C-layout == A-layout of S) ----
            f32x4 sacc[2][4];
            #pragma unroll
            for (int st = 0; st < 2; ++st)
                #pragma unroll
                for (int s = 0; s < 4; ++s) sacc[st][s] = (f32x4){0.f, 0.f, 0.f, 0.f};
            #pragma unroll
            for (int s = 0; s < 4; ++s) {
                #pragma unroll
                for (int ks = 0; ks < 2; ++ks) {
                    U8 ak; ak.u = *(const u16x8*)&Kb[swzoff(s * 16 + a, ks * 4 + quad)];
                    #pragma unroll
                    for (int st = 0; st < 2; ++st)
                        sacc[st][s] = __builtin_amdgcn_mfma_f32_16x16x32_f16(
                            ak.f, bQ[st][ks], sacc[st][s], 0, 0, 0);
                }
            }
            // ---- square, mask (diag), den, convert in-register ----
            const bool diag = (kt == Tq);
            f16x4 aS[2][4];
            #pragma unroll
            for (int st = 0; st < 2; ++st) {
                const int qrow = w2 * 32 + st * 16 + a;
                #pragma unroll
                for (int s = 0; s < 4; ++s) {
                    float pv[4];
                    #pragma unroll
                    for (int r = 0; r < 4; ++r) {
                        float d0 = sacc[st][s][r];
                        float v = d0 * d0;
                        if (diag && (s * 16 + quad * 4 + r) > qrow) v = 0.f;
                        pv[r] = v;
                    }
                    den[st] += (pv[0] + pv[1]) + (pv[2] + pv[3]);
                    aS[st][s] = (f16x4){(_Float16)pv[0], (_Float16)pv[1],
                                        (_Float16)pv[2], (_Float16)pv[3]};
                }
            }
            // ---- PV: O += S·V via 16x16x16; S^T C-regs feed A directly ----
            #pragma unroll
            for (int n = 0; n < 4; ++n) {
                U8 va, vb_;
                va.u  = *(const u16x8*)&Vb[swzoff(n * 16 + a, quad * 2)];
                vb_.u = *(const u16x8*)&Vb[swzoff(n * 16 + a, quad * 2 + 1)];
                #pragma unroll
                for (int st = 0; st < 2; ++st) {
                    oacc[st][n] = __builtin_amdgcn_mfma_f32_16x16x16f16(aS[st][0], va.q[0],  oacc[st][n], 0, 0, 0);
                    oacc[st][n] = __builtin_amdgcn_mfma_f32_16x16x16f16(aS[st][1], va.q[1],  oacc[st][n], 0, 0, 0);
                    oacc[st][n] = __builtin_amdgcn_mfma_f32_16x16x16f16(aS[st][2], vb_.q[0], oacc[st][n], 0, 0, 0);
                    oacc[st][n] = __builtin_amdgcn_mfma_f32_16x16x16f16(aS[st][3], vb_.q[1], oacc[st][n], 0, 0, 0);
                }
            }
        }
        __syncthreads();   // all reads done (WAR for next stage / epilogue E1)

        if (it == IA - 1 || it == 8) {
            // ======== phase epilogue: combine 4 key-groups, divide, store ========
            float d0 = den[0], d1 = den[1];
            d0 += __shfl_xor(d0, 16); d0 += __shfl_xor(d0, 32);
            d1 += __shfl_xor(d1, 16); d1 += __shfl_xor(d1, 32);
            float* Op = (float*)lds;                 // [6][32 rows][65] padded f32
            float* Dp = (float*)lds + 6 * 32 * 65;   // [4g][2w2][2st][16a]
            if (g > 0) {
                const int base = ((g - 1) * 2 + w2) * (32 * 65);
                #pragma unroll
                for (int st = 0; st < 2; ++st)
                    #pragma unroll
                    for (int n = 0; n < 4; ++n)
                        #pragma unroll
                        for (int r = 0; r < 4; ++r)
                            Op[base + (st * 16 + quad * 4 + r) * 65 + n * 16 + a] = oacc[st][n][r];
            }
            if (quad == 0) {
                Dp[((g * 2 + w2) * 2 + 0) * 16 + a] = d0;
                Dp[((g * 2 + w2) * 2 + 1) * 16 + a] = d1;
            }
            __syncthreads();
            if (g == 0) {
                #pragma unroll
                for (int st = 0; st < 2; ++st) {
                    float invz[4];
                    #pragma unroll
                    for (int r = 0; r < 4; ++r) {
                        float s = 1e-5f;
                        #pragma unroll
                        for (int gg = 0; gg < 4; ++gg)
                            s += Dp[((gg * 2 + w2) * 2 + st) * 16 + quad * 4 + r];
                        invz[r] = 1.0f / s;
                    }
                    #pragma unroll
                    for (int n = 0; n < 4; ++n) {
                        f32x4 o = oacc[st][n];
                        #pragma unroll
                        for (int gg = 1; gg < 4; ++gg) {
                            const int base = ((gg - 1) * 2 + w2) * (32 * 65);
                            #pragma unroll
                            for (int r = 0; r < 4; ++r)
                                o[r] += Op[base + (st * 16 + quad * 4 + r) * 65 + n * 16 + a];
                        }
                        #pragma unroll
                        for (int r = 0; r < 4; ++r) {
                            const int t = Tq * 64 + w2 * 32 + st * 16 + quad * 4 + r;
                            Og[(((size_t)b * 2048 + t) * 8 + h) * 64 + n * 16 + a] = o[r] * invz[r];
                        }
                    }
                }
            }
            __syncthreads();   // E3: combine reads done before next staging writes
            if (it == IA - 1) {  // reset accumulators, load phase-B Q frags
                #pragma unroll
                for (int st = 0; st < 2; ++st) {
                    den[st] = 0.f;
                    #pragma unroll
                    for (int n = 0; n < 4; ++n) oacc[st][n] = (f32x4){0.f, 0.f, 0.f, 0.f};
                }
                loadBQ(TqB);
            }
        }
    }
}

extern "C" void kernel_launch(void* const* d_in, const int* in_sizes, int n_in,
                              void* d_out, int out_size, void* d_ws, size_t ws_size,
                              hipStream_t stream) {
    const float* Q = (const float*)d_in[0];
    const float* K = (const float*)d_in[1];
    const float* V = (const float*)d_in[2];
    float* O = (float*)d_out;
    unsigned short* Kw = (unsigned short*)d_ws;                 // 4 MB
    unsigned short* Vw = Kw + (size_t)16 * 32 * TILE_SHORTS;    // 4 MB

    prepass<<<dim3(32, 16), 256, 0, stream>>>(K, V, Kw, Vw);
    attn_pow2_f16<<<dim3(256), NT, 0, stream>>>(Q, Kw, Vw, O);
}

// Round 8
// 95.901 us; speedup vs baseline: 1.0683x; 1.0399x over previous
//
#include <hip/hip_runtime.h>
#include <hip/hip_fp16.h>

typedef __attribute__((ext_vector_type(8))) _Float16 f16x8;
typedef __attribute__((ext_vector_type(4))) _Float16 f16x4;
typedef __attribute__((ext_vector_type(8))) unsigned short u16x8;
typedef __attribute__((ext_vector_type(4))) float f32x4;

constexpr int NT = 256;
constexpr int TILE_SHORTS = 4096;   // 64 rows x 64 fp16 = 8KB tile image

// phys 16B-chunk swizzle: row r, logical chunk c (0..7) -> short offset
__device__ __forceinline__ int swzoff(int row, int c) {
    return row * 64 + ((c ^ (row & 7)) << 3);
}
__device__ __forceinline__ unsigned short f2h_u(float x) {
    return __half_as_ushort(__float2half(x));
}

// ============ pre-pass: f32 -> fp16 swizzled tile images in ws ============
__global__ __launch_bounds__(256, 4) void prepass(
    const float* __restrict__ Kg, const float* __restrict__ Vg,
    unsigned short* __restrict__ Kw, unsigned short* __restrict__ Vw)
{
    __shared__ __align__(16) float Vl[64 * 68];
    const int tile = blockIdx.x;      // 0..31
    const int bh   = blockIdx.y;      // 0..15
    const int b = bh >> 3, h = bh & 7;
    const int tid = threadIdx.x;
    const size_t gbase = (((size_t)b * 2048 + tile * 64) * 8 + h) * 64;

    // stage V tile f32 into LDS (coalesced)
    #pragma unroll
    for (int j = 0; j < 4; ++j) {
        int id = j * 256 + tid, row = id >> 4, c4 = id & 15;
        *(float4*)&Vl[row * 68 + c4 * 4] =
            *(const float4*)&Vg[gbase + (size_t)row * 512 + c4 * 4];
    }

    // K image: row-major fp16, 16B chunks XOR-swizzled
    unsigned short* Ko = Kw + (size_t)(bh * 32 + tile) * TILE_SHORTS;
    #pragma unroll
    for (int j = 0; j < 2; ++j) {
        int id = j * 256 + tid, row = id >> 3, c = id & 7;
        const float* src = &Kg[gbase + (size_t)row * 512 + c * 8];
        float4 x = *(const float4*)src, y = *(const float4*)(src + 4);
        u16x8 o;
        o[0] = f2h_u(x.x); o[1] = f2h_u(x.y); o[2] = f2h_u(x.z); o[3] = f2h_u(x.w);
        o[4] = f2h_u(y.x); o[5] = f2h_u(y.y); o[6] = f2h_u(y.z); o[7] = f2h_u(y.w);
        *(u16x8*)&Ko[swzoff(row, c)] = o;
    }
    __syncthreads();

    // V^T image, k-permuted so one b128 = the 4 B-frags of 16x16x16 PV:
    // store at k' = quad*16 + c*4 + i the element k = c*16 + quad*4 + i
    unsigned short* Vo = Vw + (size_t)(bh * 32 + tile) * TILE_SHORTS;
    #pragma unroll
    for (int j = 0; j < 2; ++j) {
        int id = j * 256 + tid, vrow = id >> 3, g = id & 7;
        u16x8 o;
        #pragma unroll
        for (int jj = 0; jj < 8; ++jj) {
            int kk = ((g & 1) * 2 + (jj >> 2)) * 16 + (g >> 1) * 4 + (jj & 3);
            o[jj] = f2h_u(Vl[kk * 68 + vrow]);
        }
        *(u16x8*)&Vo[swzoff(vrow, g)] = o;
    }
}

// ============ main kernel (R5 structure — measured best) ============
__global__ __launch_bounds__(NT, 3) void attn_pow2_f16(
    const float* __restrict__ Qg,
    const unsigned short* __restrict__ Kw, const unsigned short* __restrict__ Vw,
    float* __restrict__ Og)
{
    __shared__ __align__(16) unsigned short lds[4 * TILE_SHORTS];  // 32 KiB
    unsigned short* const Kb = lds;                    // 2 buffers
    unsigned short* const Vb = lds + 2 * TILE_SHORTS;  // 2 buffers
    const int tid  = threadIdx.x;
    const int lane = tid & 63;
    const int wave = tid >> 6;
    const int a    = lane & 15;
    const int quad = lane >> 4;
    const int m0   = wave * 16;

    // heavy+light pairing swizzle (bijection over 512 blocks)
    int r0 = (int)blockIdx.x;
    int wr = (r0 < 256) ? r0 : (767 - r0);
    const int qt = 31 - (wr >> 4);
    const int bh = wr & 15;
    const int b = bh >> 3, h = bh & 7;
    const int q0 = qt * 64;

    // ---- Q B-frags from global f32: B[n=q=a][k=d=ks*32+quad*8+j] ----
    f16x8 bQ[2];
    {
        const size_t qrowbase = (((size_t)b * 2048 + q0 + m0 + a) * 8 + h) * 64;
        #pragma unroll
        for (int ks = 0; ks < 2; ++ks) {
            const float* src = &Qg[qrowbase + ks * 32 + quad * 8];
            float4 x = *(const float4*)src, y = *(const float4*)(src + 4);
            u16x8 o;
            o[0] = f2h_u(x.x); o[1] = f2h_u(x.y); o[2] = f2h_u(x.z); o[3] = f2h_u(x.w);
            o[4] = f2h_u(y.x); o[5] = f2h_u(y.y); o[6] = f2h_u(y.z); o[7] = f2h_u(y.w);
            bQ[ks] = __builtin_bit_cast(f16x8, o);
        }
    }

    const unsigned short* Ktiles = Kw + (size_t)bh * 32 * TILE_SHORTS;
    const unsigned short* Vtiles = Vw + (size_t)bh * 32 * TILE_SHORTS;

    // register-staged tile prefetch (byte-copy of pre-swizzled images)
    u16x8 rK[2], rV[2];
    auto gload = [&](int kt) {
        const u16x8* kg = (const u16x8*)(Ktiles + (size_t)kt * TILE_SHORTS);
        const u16x8* vg = (const u16x8*)(Vtiles + (size_t)kt * TILE_SHORTS);
        rK[0] = kg[tid * 2]; rK[1] = kg[tid * 2 + 1];
        rV[0] = vg[tid * 2]; rV[1] = vg[tid * 2 + 1];
    };
    gload(0);

    f32x4 oacc[4];
    #pragma unroll
    for (int n = 0; n < 4; ++n) oacc[n] = (f32x4){0.f, 0.f, 0.f, 0.f};
    float den_l = 0.f;

    union U8 { u16x8 u; f16x4 q[2]; f16x8 f; };

    for (int kt = 0; kt <= qt; ++kt) {
        const int buf = kt & 1;
        u16x8* kd = (u16x8*)(Kb + buf * TILE_SHORTS);
        u16x8* vd = (u16x8*)(Vb + buf * TILE_SHORTS);
        kd[tid * 2] = rK[0]; kd[tid * 2 + 1] = rK[1];
        vd[tid * 2] = rV[0]; vd[tid * 2 + 1] = rV[1];
        __syncthreads();   // single barrier: buf complete; WAR is 2 barriers back
        if (kt < qt) gload(kt + 1);   // drains during this tile's compute

        const unsigned short* Kc = Kb + buf * TILE_SHORTS;
        const unsigned short* Vc = Vb + buf * TILE_SHORTS;

        // ---- S^T = K·Q^T per 16-row k-strip: C-layout == A-layout of S ----
        f32x4 sacc[4];
        #pragma unroll
        for (int s = 0; s < 4; ++s) sacc[s] = (f32x4){0.f, 0.f, 0.f, 0.f};
        #pragma unroll
        for (int s = 0; s < 4; ++s) {
            #pragma unroll
            for (int ks = 0; ks < 2; ++ks) {
                U8 ak; ak.u = *(const u16x8*)&Kc[swzoff(s * 16 + a, ks * 4 + quad)];
                sacc[s] = __builtin_amdgcn_mfma_f32_16x16x32_f16(ak.f, bQ[ks], sacc[s], 0, 0, 0);
            }
        }

        // ---- square, mask (diag), den, convert in-register ----
        const bool diag = (kt == qt);
        f16x4 aS[4];
        #pragma unroll
        for (int s = 0; s < 4; ++s) {
            float p[4];
            #pragma unroll
            for (int r = 0; r < 4; ++r) {
                float d0 = sacc[s][r];
                float v = d0 * d0;
                if (diag && (s * 16 + quad * 4 + r) > (m0 + a)) v = 0.f;
                p[r] = v;
            }
            den_l += (p[0] + p[1]) + (p[2] + p[3]);
            aS[s] = (f16x4){(_Float16)p[0], (_Float16)p[1], (_Float16)p[2], (_Float16)p[3]};
        }

        // ---- PV: O += S·V via 16x16x16, S^T C-regs feed A directly ----
        #pragma unroll
        for (int n = 0; n < 4; ++n) {
            U8 va, vb;
            va.u = *(const u16x8*)&Vc[swzoff(n * 16 + a, quad * 2)];
            vb.u = *(const u16x8*)&Vc[swzoff(n * 16 + a, quad * 2 + 1)];
            oacc[n] = __builtin_amdgcn_mfma_f32_16x16x16f16(aS[0], va.q[0], oacc[n], 0, 0, 0);
            oacc[n] = __builtin_amdgcn_mfma_f32_16x16x16f16(aS[1], va.q[1], oacc[n], 0, 0, 0);
            oacc[n] = __builtin_amdgcn_mfma_f32_16x16x16f16(aS[2], vb.q[0], oacc[n], 0, 0, 0);
            oacc[n] = __builtin_amdgcn_mfma_f32_16x16x16f16(aS[3], vb.q[1], oacc[n], 0, 0, 0);
        }
    }

    // ---- den: reduce across quads (same q=a), then gather per output row ----
    den_l += __shfl_xor(den_l, 16);
    den_l += __shfl_xor(den_l, 32);

    float invz[4];
    #pragma unroll
    for (int r = 0; r < 4; ++r) {
        float dq = __shfl(den_l, quad * 4 + r);   // lane holding a == quad*4+r
        invz[r] = 1.0f / (dq + 1e-5f);
    }

    #pragma unroll
    for (int n = 0; n < 4; ++n) {
        #pragma unroll
        for (int r = 0; r < 4; ++r) {
            int t = q0 + m0 + quad * 4 + r;
            int v = n * 16 + a;
            Og[(((size_t)b * 2048 + t) * 8 + h) * 64 + v] = oacc[n][r] * invz[r];
        }
    }
}

extern "C" void kernel_launch(void* const* d_in, const int* in_sizes, int n_in,
                              void* d_out, int out_size, void* d_ws, size_t ws_size,
                              hipStream_t stream) {
    const float* Q = (const float*)d_in[0];
    const float* K = (const float*)d_in[1];
    const float* V = (const float*)d_in[2];
    float* O = (float*)d_out;
    unsigned short* Kw = (unsigned short*)d_ws;                 // 4 MB
    unsigned short* Vw = Kw + (size_t)16 * 32 * TILE_SHORTS;    // 4 MB

    prepass<<<dim3(32, 16), 256, 0, stream>>>(K, V, Kw, Vw);
    attn_pow2_f16<<<dim3(512), NT, 0, stream>>>(Q, Kw, Vw, O);
}